// Round 1
// baseline (136.719 us; speedup 1.0000x reference)
//
#include <hip/hip_runtime.h>
#include <math.h>

#define P_DIM 128
#define K_CLS 1000
#define K_PAD 1024
#define N_TAB 4096   // table entries 0..N_TAB over kappa in [0, 50]

// ---------- reference-faithful log_Cp (f32 Miller recurrence, value-domain) ----------
__device__ __forceinline__ float i0_val(float x) {
    // Abramowitz & Stegun 9.8.1 / 9.8.2, rel err < 2e-7 (matches jax i0 within f32 noise)
    if (x <= 3.75f) {
        float t = x / 3.75f; t *= t;
        return 1.0f + t*(3.5156229f + t*(3.0899424f + t*(1.2067492f
             + t*(0.2659732f + t*(0.0360768f + t*0.0045813f)))));
    } else {
        float t = 3.75f / x;
        float p = 0.39894228f + t*(0.01328592f + t*(0.00225319f + t*(-0.00157565f
                + t*(0.00916281f + t*(-0.02057706f + t*(0.02635537f
                + t*(-0.01647633f + t*0.00392377f)))))));
        return expf(x) * p / sqrtf(x);   // x <= 50 -> expf fine in f32
    }
}

__device__ float log_Cp_dev(float kappa) {
    float k = fmaxf(kappa, 1e-8f);
    float safe_k = fmaxf(k, 1e-10f);
    // Miller backward recurrence, EXACT reference semantics:
    // captures I_curr at nu==64 (ORDER+1) and nu==1, rescale when I_prev > 1e30.
    float Ic = 1.0f, In = 0.0f, It = 0.0f, Iz = 0.0f;
    for (int nu = P_DIM; nu >= 0; --nu) {
        float coef = (2.0f * (float)nu) / safe_k;
        float Ip = fmaf(coef, Ic, In);
        if (nu == 64) It = Ic;
        if (nu == 1)  Iz = Ic;
        float sc = (Ip > 1e30f) ? 1e-30f : 1.0f;
        In = Ic * sc;
        Ic = Ip * sc;
        It *= sc;
        Iz *= sc;
    }
    float i0v = i0_val(fminf(k, 700.0f));
    float bessel = i0v / fmaxf(Iz, 1e-30f) * It;  // value-domain: replicate under/overflow path
    bessel = fmaxf(bessel, 1e-30f);
    float lb = logf(bessel);
    float v = 63.0f * logf(k) - 117.62413225019811f - lb;  // 63 log k - 64 log(2pi) - log_bessel
    return fminf(fmaxf(v, -500.0f), 500.0f);
}

// ---------- table of log_Cp over [0,50], step 50/4096 (exact at node 4096 = 50.0) ----------
__global__ void table_kernel(float* __restrict__ T) {
    int i = blockIdx.x * blockDim.x + threadIdx.x;
    if (i > N_TAB) return;
    if (i == 0) { T[0] = -500.0f; return; }   // clip region; avoids f32 overflow at k~1e-8
    float k = (float)i * (50.0f / 4096.0f);
    T[i] = log_Cp_dev(k);
}

// ---------- per-class: mu, kappa, km (transposed), sq, log_pi - log_Cp(kappa) ----------
__global__ __launch_bounds__(64) void cls_kernel(
    const float* __restrict__ z_bar, const float* __restrict__ prior,
    float* __restrict__ kmT, float* __restrict__ cls_c, float* __restrict__ cls_sq)
{
    const int k = blockIdx.x;       // 0..K_PAD-1
    const int lane = threadIdx.x;   // 64 = one wave
    if (k >= K_CLS) {               // padding classes: km=0, lr forced to -500
        kmT[(lane >> 2) * (K_PAD * 4) + k * 4 + (lane & 3)] = 0.0f;
        int p1 = lane + 64;
        kmT[(p1 >> 2) * (K_PAD * 4) + k * 4 + (p1 & 3)] = 0.0f;
        if (lane == 0) { cls_c[k] = -1.0e4f; cls_sq[k] = 0.0f; }
        return;
    }
    float zb0 = z_bar[k * P_DIM + lane];
    float zb1 = z_bar[k * P_DIM + 64 + lane];
    zb0 = isnan(zb0) ? 0.0f : zb0;
    zb1 = isnan(zb1) ? 0.0f : zb1;
    float ss = fmaf(zb0, zb0, zb1 * zb1);
    #pragma unroll
    for (int off = 32; off >= 1; off >>= 1) ss += __shfl_xor(ss, off, 64);
    float nrm = sqrtf(ss);
    float R = fminf(fmaxf(nrm, 0.0f), 1.0f - 1e-6f);
    float Rc = fmaxf(R, 1e-8f);
    bool ok = R > 1e-8f;
    float mu0 = ok ? zb0 / Rc : 0.0f;
    float mu1 = ok ? zb1 / Rc : 0.0f;
    float ms = fmaf(mu0, mu0, mu1 * mu1);
    #pragma unroll
    for (int off = 32; off >= 1; off >>= 1) ms += __shfl_xor(ms, off, 64);
    float mden = fmaxf(sqrtf(ms), 1e-8f);
    mu0 /= mden; mu1 /= mden;
    float R2 = R * R;
    float kap = fminf(fmaxf(R * (128.0f - R2) / fmaxf(1.0f - R2, 1e-8f), 1e-3f), 50.0f);
    float km0 = kap * mu0, km1 = kap * mu1;
    float sq = fmaf(km0, km0, km1 * km1);
    #pragma unroll
    for (int off = 32; off >= 1; off >>= 1) sq += __shfl_xor(sq, off, 64);
    // store transposed: kmT[chunk][class] as float4 -> float idx = chunk*(K_PAD*4) + k*4 + sub
    kmT[(lane >> 2) * (K_PAD * 4) + k * 4 + (lane & 3)] = km0;
    int p1 = lane + 64;
    kmT[(p1 >> 2) * (K_PAD * 4) + k * 4 + (p1 & 3)] = km1;
    if (lane == 0) {
        float lcp = log_Cp_dev(kap);  // exact Miller for the per-class term
        cls_c[k] = logf(fmaxf(prior[k], 1e-8f)) - lcp;
        cls_sq[k] = sq;
    }
}

// ---------- main: 16 rows/block, 4 rows x 8 classes register tile, online LSE ----------
__global__ __launch_bounds__(256) void main_kernel(
    const float* __restrict__ feats, const int* __restrict__ labels,
    const float4* __restrict__ kmT4, const float* __restrict__ cls_c,
    const float* __restrict__ cls_sq, const float* __restrict__ T,
    float* __restrict__ rowloss)
{
    __shared__ float4 zs4[16][32];
    __shared__ float zsq_s[16];
    __shared__ int   lab_s[16];
    __shared__ float num_s[16];

    const int t = threadIdx.x;
    const int lane = t & 63;
    const int wave = t >> 6;          // 4 waves, wave w owns rows 4w..4w+3
    const int rowbase = blockIdx.x * 16;
    float* zs = (float*)zs4;

    // prologue: normalize rows (F.normalize + /TAU), compute zsq
    #pragma unroll
    for (int rr = 0; rr < 4; ++rr) {
        const int r = wave * 4 + rr;
        const float* f = feats + (size_t)(rowbase + r) * P_DIM;
        float2 v = *(const float2*)(f + lane * 2);
        float ss = fmaf(v.x, v.x, v.y * v.y);
        #pragma unroll
        for (int off = 32; off >= 1; off >>= 1) ss += __shfl_xor(ss, off, 64);
        float nrm = fmaxf(sqrtf(ss), 1e-8f);
        float z0 = (v.x / nrm) / 0.1f;
        float z1 = (v.y / nrm) / 0.1f;
        float zq = fmaf(z0, z0, z1 * z1);
        #pragma unroll
        for (int off = 32; off >= 1; off >>= 1) zq += __shfl_xor(zq, off, 64);
        zs[r * 128 + lane * 2]     = z0;
        zs[r * 128 + lane * 2 + 1] = z1;
        if (lane == 0) { zsq_s[r] = zq; lab_s[r] = labels[rowbase + r]; }
    }
    __syncthreads();

    const int r0 = wave * 4;
    float zsqv[4]; int labv[4];
    #pragma unroll
    for (int r = 0; r < 4; ++r) { zsqv[r] = zsq_s[r0 + r]; labv[r] = lab_s[r0 + r]; }

    float m[4], s[4];
    #pragma unroll
    for (int r = 0; r < 4; ++r) { m[r] = -1e30f; s[r] = 0.0f; }

    #pragma unroll
    for (int i = 0; i < 2; ++i) {                 // 2 passes x 512 classes
        float acc[4][8];
        #pragma unroll
        for (int r = 0; r < 4; ++r)
            #pragma unroll
            for (int j = 0; j < 8; ++j) acc[r][j] = 0.0f;

        for (int c = 0; c < 32; ++c) {            // 128 features as 32 float4 chunks
            float4 km[8];
            #pragma unroll
            for (int j = 0; j < 8; ++j)
                km[j] = kmT4[c * K_PAD + i * 512 + j * 64 + lane];   // coalesced
            #pragma unroll
            for (int r = 0; r < 4; ++r) {
                float4 z = zs4[r0 + r][c];        // LDS broadcast (conflict-free)
                #pragma unroll
                for (int j = 0; j < 8; ++j) {
                    acc[r][j] = fmaf(z.x, km[j].x, acc[r][j]);
                    acc[r][j] = fmaf(z.y, km[j].y, acc[r][j]);
                    acc[r][j] = fmaf(z.z, km[j].z, acc[r][j]);
                    acc[r][j] = fmaf(z.w, km[j].w, acc[r][j]);
                }
            }
        }
        #pragma unroll
        for (int j = 0; j < 8; ++j) {
            const int k = i * 512 + j * 64 + lane;
            const float cc = cls_c[k];
            const float sq = cls_sq[k];
            #pragma unroll
            for (int r = 0; r < 4; ++r) {
                float kt2 = fmaxf(sq + 2.0f * acc[r][j] + zsqv[r], 0.0f);
                float kt = fminf(fmaxf(sqrtf(kt2), 1e-4f), 50.0f);
                float x = kt * (4096.0f / 50.0f);
                int idx = (int)x;
                idx = idx > (N_TAB - 1) ? (N_TAB - 1) : idx;
                float fr = x - (float)idx;
                float t0 = T[idx];
                float t1 = T[idx + 1];
                float lcp = fmaf(fr, t1 - t0, t0);
                float lr = cc + lcp;
                lr = fminf(fmaxf(lr, -500.0f), 500.0f);
                float nm = fmaxf(m[r], lr);
                s[r] = fmaf(s[r], __expf(m[r] - nm), __expf(lr - nm));
                m[r] = nm;
                if (k == labv[r]) num_s[r0 + r] = lr;   // exactly one writer per row
            }
        }
    }

    // combine (m,s) across 64 lanes of the wave
    #pragma unroll
    for (int off = 1; off < 64; off <<= 1) {
        #pragma unroll
        for (int r = 0; r < 4; ++r) {
            float om = __shfl_xor(m[r], off, 64);
            float os = __shfl_xor(s[r], off, 64);
            float nm = fmaxf(m[r], om);
            s[r] = s[r] * __expf(m[r] - nm) + os * __expf(om - nm);
            m[r] = nm;
        }
    }
    __syncthreads();
    if (lane == 0) {
        #pragma unroll
        for (int r = 0; r < 4; ++r) {
            float lse = m[r] + logf(s[r]);
            rowloss[rowbase + r0 + r] = lse - num_s[r0 + r];
        }
    }
}

// ---------- deterministic final mean + nan_to_num ----------
__global__ void reduce_kernel(const float* __restrict__ rowloss, float* __restrict__ out, int B) {
    __shared__ float red[256];
    int t = threadIdx.x;
    float sum = 0.0f;
    for (int i = t; i < B; i += 256) sum += rowloss[i];
    red[t] = sum;
    __syncthreads();
    for (int o = 128; o >= 1; o >>= 1) {
        if (t < o) red[t] += red[t + o];
        __syncthreads();
    }
    if (t == 0) {
        float loss = red[0] / (float)B;
        if (isnan(loss)) loss = 0.0f;
        else if (isinf(loss)) loss = loss > 0.0f ? 10.0f : -10.0f;
        out[0] = loss;
    }
}

extern "C" void kernel_launch(void* const* d_in, const int* in_sizes, int n_in,
                              void* d_out, int out_size, void* d_ws, size_t ws_size,
                              hipStream_t stream) {
    const float* feats  = (const float*)d_in[0];   // (B,128) f32
    const int*   labels = (const int*)d_in[1];     // (B,)    i32
    const float* prior  = (const float*)d_in[2];   // (1000,) f32
    const float* z_bar  = (const float*)d_in[3];   // (1000,128) f32
    float* out = (float*)d_out;
    const int B = in_sizes[1];

    // ws layout (floats): kmT 131072 | cls_c 1024 | cls_sq 1024 | T 4104 | rowloss B
    float* ws      = (float*)d_ws;
    float* kmT     = ws;
    float* cls_c   = kmT + 32 * K_PAD * 4;
    float* cls_sq  = cls_c + K_PAD;
    float* T       = cls_sq + K_PAD;
    float* rowloss = T + 4104;

    table_kernel<<<(N_TAB + 256) / 256, 256, 0, stream>>>(T);
    cls_kernel<<<K_PAD, 64, 0, stream>>>(z_bar, prior, kmT, cls_c, cls_sq);
    main_kernel<<<B / 16, 256, 0, stream>>>(feats, labels, (const float4*)kmT,
                                            cls_c, cls_sq, T, rowloss);
    reduce_kernel<<<1, 256, 0, stream>>>(rowloss, out, B);
}

// Round 2
// 40.958 us; speedup vs baseline: 3.3380x; 3.3380x over previous
//
#include <hip/hip_runtime.h>
#include <math.h>

#define P_DIM 128
#define K_CLS 1000
#define K_PAD 1024
#define N_TAB 4096   // table nodes 0..4096 over kappa in [0,50]; node 4096 == 50.0 exactly

typedef __attribute__((ext_vector_type(8))) short short8v;   // 8 bf16 (4 VGPRs)
typedef __attribute__((ext_vector_type(4))) float f32x4;     // MFMA accumulator

// ---------- f32->bf16 round-to-nearest-even ----------
__device__ __forceinline__ unsigned short f2bf(float f) {
    unsigned int u = __float_as_uint(f);
    unsigned int r = (u + 0x7FFFu + ((u >> 16) & 1u)) >> 16;
    return (unsigned short)r;
}

// ---------- reference-faithful log_Cp (f32 Miller, value-domain) ----------
__device__ __forceinline__ float i0_val(float x) {
    if (x <= 3.75f) {
        float t = x / 3.75f; t *= t;
        return 1.0f + t*(3.5156229f + t*(3.0899424f + t*(1.2067492f
             + t*(0.2659732f + t*(0.0360768f + t*0.0045813f)))));
    } else {
        float t = 3.75f / x;
        float p = 0.39894228f + t*(0.01328592f + t*(0.00225319f + t*(-0.00157565f
                + t*(0.00916281f + t*(-0.02057706f + t*(0.02635537f
                + t*(-0.01647633f + t*0.00392377f)))))));
        return expf(x) * p / sqrtf(x);
    }
}

__device__ float log_Cp_dev(float kappa) {
    float k = fmaxf(kappa, 1e-8f);
    float inv_k = 1.0f / fmaxf(k, 1e-10f);   // hoisted: loop is fmaf-only
    float Ic = 1.0f, In = 0.0f, It = 0.0f, Iz = 0.0f;
    #pragma unroll 1
    for (int nu = P_DIM; nu >= 0; --nu) {
        float coef = (2.0f * (float)nu) * inv_k;
        float Ip = fmaf(coef, Ic, In);
        if (nu == 64) It = Ic;               // capture BEFORE rescale (ref semantics)
        if (nu == 1)  Iz = Ic;
        float sc = (Ip > 1e30f) ? 1e-30f : 1.0f;
        In = Ic * sc; Ic = Ip * sc; It *= sc; Iz *= sc;
    }
    float i0v = i0_val(fminf(k, 700.0f));
    float bessel = fmaxf(i0v / fmaxf(Iz, 1e-30f) * It, 1e-30f);
    float v = 63.0f * logf(k) - 117.62413225019811f - logf(bessel);
    return fminf(fmaxf(v, -500.0f), 500.0f);
}

// ---------- k1: fused cls-prep (blocks 0..63) + table (blocks 64..80) ----------
__global__ __launch_bounds__(256) void prep_kernel(
    const float* __restrict__ z_bar, const float* __restrict__ prior,
    short8v* __restrict__ kmF, float* __restrict__ cls_c, float* __restrict__ cls_sq,
    float* __restrict__ T)
{
    const int bid = blockIdx.x;
    const int t = threadIdx.x;

    if (bid >= 64) {                       // ---- table role ----
        int i = (bid - 64) * 256 + t;
        if (i <= N_TAB) T[i] = log_Cp_dev((float)i * (50.0f / 4096.0f));
        return;
    }

    // ---- cls role: 16 classes per block ----
    __shared__ float kmS[16][132];         // km rows f32 (pad -> 16B-aligned frag reads)
    __shared__ float kapS[16];
    const int w = t >> 6, lane = t & 63;

    #pragma unroll
    for (int rr = 0; rr < 4; ++rr) {
        const int kc = w * 4 + rr;
        const int k = bid * 16 + kc;
        if (k < K_CLS) {
            float zb0 = z_bar[k * P_DIM + lane];
            float zb1 = z_bar[k * P_DIM + 64 + lane];
            zb0 = isnan(zb0) ? 0.0f : zb0;
            zb1 = isnan(zb1) ? 0.0f : zb1;
            float ss = fmaf(zb0, zb0, zb1 * zb1);
            #pragma unroll
            for (int off = 32; off >= 1; off >>= 1) ss += __shfl_xor(ss, off, 64);
            float R = fminf(fmaxf(sqrtf(ss), 0.0f), 1.0f - 1e-6f);
            float Rc = fmaxf(R, 1e-8f);
            bool ok = R > 1e-8f;
            float mu0 = ok ? zb0 / Rc : 0.0f;
            float mu1 = ok ? zb1 / Rc : 0.0f;
            float ms = fmaf(mu0, mu0, mu1 * mu1);
            #pragma unroll
            for (int off = 32; off >= 1; off >>= 1) ms += __shfl_xor(ms, off, 64);
            float mden = fmaxf(sqrtf(ms), 1e-8f);
            mu0 /= mden; mu1 /= mden;
            float R2 = R * R;
            float kap = fminf(fmaxf(R * (128.0f - R2) / fmaxf(1.0f - R2, 1e-8f), 1e-3f), 50.0f);
            float km0 = kap * mu0, km1 = kap * mu1;
            float sq = fmaf(km0, km0, km1 * km1);
            #pragma unroll
            for (int off = 32; off >= 1; off >>= 1) sq += __shfl_xor(sq, off, 64);
            kmS[kc][lane] = km0; kmS[kc][64 + lane] = km1;
            if (lane == 0) { kapS[kc] = kap; cls_sq[k] = sq; }
        } else {
            kmS[kc][lane] = 0.0f; kmS[kc][64 + lane] = 0.0f;
            if (lane == 0) { kapS[kc] = -1.0f; cls_sq[k] = 0.0f; }
        }
    }
    __syncthreads();

    if (w == 0) {                          // exact Miller: 16 classes in parallel lanes
        float kap = kapS[lane & 15];
        float lcp = log_Cp_dev(fmaxf(kap, 1e-3f));
        if (lane < 16) {
            int k = bid * 16 + lane;
            cls_c[k] = (kap < 0.0f) ? -1.0e4f
                     : (logf(fmaxf(prior[k], 1e-8f)) - lcp);
        }
    }

    // fragments: wave = K-step ks; B-frag convention: entity(col)=lane&15,
    // k elems = ks*32 + (lane>>4)*8 .. +7 (k-permutation cancels: A uses same)
    {
        const int ks = w;
        const float* src = &kmS[lane & 15][ks * 32 + (lane >> 4) * 8];
        float4 a = *(const float4*)src;
        float4 b = *(const float4*)(src + 4);
        short8v fr;
        fr[0] = (short)f2bf(a.x); fr[1] = (short)f2bf(a.y);
        fr[2] = (short)f2bf(a.z); fr[3] = (short)f2bf(a.w);
        fr[4] = (short)f2bf(b.x); fr[5] = (short)f2bf(b.y);
        fr[6] = (short)f2bf(b.z); fr[7] = (short)f2bf(b.w);
        kmF[(bid * 4 + ks) * 64 + lane] = fr;
    }
}

// ---------- k2: main — 16 rows x 512 classes per block (split-K over classes) ----------
__global__ __launch_bounds__(256, 4) void main_kernel(
    const float* __restrict__ feats, const int* __restrict__ labels,
    const short8v* __restrict__ kmF, const float* __restrict__ cls_c,
    const float* __restrict__ cls_sq, const float* __restrict__ Tg,
    float* __restrict__ Pm, float* __restrict__ Ps, float* __restrict__ Pn)
{
    __shared__ float Ts[N_TAB + 1];
    __shared__ float zS[16][132];
    __shared__ float zsq_s[16];
    __shared__ int   lab_s[16];
    __shared__ float pm[4][16], ps[4][16], pn[4][16];

    const int t = threadIdx.x;
    const int lane = t & 63;
    const int w = t >> 6;
    const int rb = blockIdx.x >> 1;
    const int half = blockIdx.x & 1;

    for (int i = t; i <= N_TAB; i += 256) Ts[i] = Tg[i];

    // normalize 16 rows (4 per wave); z/tau into LDS f32
    #pragma unroll
    for (int rr = 0; rr < 4; ++rr) {
        const int r = w * 4 + rr;
        const float* f = feats + (size_t)(rb * 16 + r) * P_DIM;
        float2 v = *(const float2*)(f + lane * 2);
        float ss = fmaf(v.x, v.x, v.y * v.y);
        #pragma unroll
        for (int off = 32; off >= 1; off >>= 1) ss += __shfl_xor(ss, off, 64);
        float nrm = fmaxf(sqrtf(ss), 1e-8f);
        float z0 = (v.x / nrm) / 0.1f;
        float z1 = (v.y / nrm) / 0.1f;
        float zq = fmaf(z0, z0, z1 * z1);
        #pragma unroll
        for (int off = 32; off >= 1; off >>= 1) zq += __shfl_xor(zq, off, 64);
        zS[r][2 * lane] = z0; zS[r][2 * lane + 1] = z1;
        if (lane == 0) { zsq_s[r] = zq; lab_s[r] = labels[rb * 16 + r]; }
    }
    __syncthreads();

    // A-fragments (4 K-steps), same convention as B
    short8v aF[4];
    #pragma unroll
    for (int ks = 0; ks < 4; ++ks) {
        const float* src = &zS[lane & 15][ks * 32 + (lane >> 4) * 8];
        float4 a = *(const float4*)src;
        float4 b = *(const float4*)(src + 4);
        short8v fr;
        fr[0] = (short)f2bf(a.x); fr[1] = (short)f2bf(a.y);
        fr[2] = (short)f2bf(a.z); fr[3] = (short)f2bf(a.w);
        fr[4] = (short)f2bf(b.x); fr[5] = (short)f2bf(b.y);
        fr[6] = (short)f2bf(b.z); fr[7] = (short)f2bf(b.w);
        aF[ks] = fr;
    }

    const int g = lane >> 4;
    float zsqv[4], numv[4], m[4], s[4]; int labv[4];
    #pragma unroll
    for (int r = 0; r < 4; ++r) {
        zsqv[r] = zsq_s[g * 4 + r]; labv[r] = lab_s[g * 4 + r];
        m[r] = -1e30f; s[r] = 0.0f; numv[r] = -1e30f;
    }

    const int cb0 = (half * 512 + w * 128) >> 4;   // this wave's first class-16-tile

    for (int t8 = 0; t8 < 8; ++t8) {
        const int cb = cb0 + t8;
        short8v b0 = kmF[(cb * 4 + 0) * 64 + lane];
        short8v b1 = kmF[(cb * 4 + 1) * 64 + lane];
        short8v b2 = kmF[(cb * 4 + 2) * 64 + lane];
        short8v b3 = kmF[(cb * 4 + 3) * 64 + lane];
        f32x4 acc = {0.0f, 0.0f, 0.0f, 0.0f};
        acc = __builtin_amdgcn_mfma_f32_16x16x32_bf16(aF[0], b0, acc, 0, 0, 0);
        acc = __builtin_amdgcn_mfma_f32_16x16x32_bf16(aF[1], b1, acc, 0, 0, 0);
        acc = __builtin_amdgcn_mfma_f32_16x16x32_bf16(aF[2], b2, acc, 0, 0, 0);
        acc = __builtin_amdgcn_mfma_f32_16x16x32_bf16(aF[3], b3, acc, 0, 0, 0);

        const int c = (cb << 4) + (lane & 15);     // class of this lane's column
        const float cc = cls_c[c];
        const float sqc = cls_sq[c];
        #pragma unroll
        for (int r = 0; r < 4; ++r) {
            float kt2 = fmaxf(fmaf(2.0f, acc[r], sqc + zsqv[r]), 0.0f);
            float kt = fminf(fmaxf(sqrtf(kt2), 1e-4f), 50.0f);
            float x = kt * (4096.0f / 50.0f);
            int idx = (int)x;
            idx = idx > (N_TAB - 1) ? (N_TAB - 1) : idx;
            float frc = x - (float)idx;
            float t0 = Ts[idx], t1 = Ts[idx + 1];
            float lr = cc + fmaf(frc, t1 - t0, t0);
            lr = fminf(fmaxf(lr, -500.0f), 500.0f);
            numv[r] = (c == labv[r]) ? lr : numv[r];
            float nm = fmaxf(m[r], lr);
            s[r] = fmaf(s[r], __expf(m[r] - nm), __expf(lr - nm));
            m[r] = nm;
        }
    }

    // combine across the 16 lanes sharing this row-group
    #pragma unroll
    for (int off = 1; off < 16; off <<= 1) {
        #pragma unroll
        for (int r = 0; r < 4; ++r) {
            float om = __shfl_xor(m[r], off, 64);
            float os = __shfl_xor(s[r], off, 64);
            float nm = fmaxf(m[r], om);
            s[r] = s[r] * __expf(m[r] - nm) + os * __expf(om - nm);
            m[r] = nm;
            numv[r] = fmaxf(numv[r], __shfl_xor(numv[r], off, 64));
        }
    }
    if ((lane & 15) == 0) {
        #pragma unroll
        for (int r = 0; r < 4; ++r) {
            pm[w][g * 4 + r] = m[r]; ps[w][g * 4 + r] = s[r]; pn[w][g * 4 + r] = numv[r];
        }
    }
    __syncthreads();
    if (t < 16) {
        float M = -1e30f, S = 0.0f, N = -1e30f;
        #pragma unroll
        for (int w2 = 0; w2 < 4; ++w2) {
            float mm = pm[w2][t], ss2 = ps[w2][t];
            float nm = fmaxf(M, mm);
            S = S * __expf(M - nm) + ss2 * __expf(mm - nm);
            M = nm;
            N = fmaxf(N, pn[w2][t]);
        }
        const int row = rb * 16 + t;
        Pm[row * 2 + half] = M; Ps[row * 2 + half] = S; Pn[row * 2 + half] = N;
    }
}

// ---------- k3: deterministic combine + mean + nan_to_num ----------
__global__ __launch_bounds__(1024) void reduce_kernel(
    const float* __restrict__ Pm, const float* __restrict__ Ps,
    const float* __restrict__ Pn, float* __restrict__ out, int B)
{
    __shared__ float red[1024];
    const int t = threadIdx.x;
    float sum = 0.0f;
    for (int r = t; r < B; r += 1024) {
        float m0 = Pm[r * 2], m1 = Pm[r * 2 + 1];
        float s0 = Ps[r * 2], s1 = Ps[r * 2 + 1];
        float M = fmaxf(m0, m1);
        float S = s0 * __expf(m0 - M) + s1 * __expf(m1 - M);
        float lse = M + logf(S);
        float num = fmaxf(Pn[r * 2], Pn[r * 2 + 1]);
        sum += lse - num;
    }
    red[t] = sum;
    __syncthreads();
    for (int o = 512; o >= 1; o >>= 1) {
        if (t < o) red[t] += red[t + o];
        __syncthreads();
    }
    if (t == 0) {
        float loss = red[0] / (float)B;
        if (isnan(loss)) loss = 0.0f;
        else if (isinf(loss)) loss = loss > 0.0f ? 10.0f : -10.0f;
        out[0] = loss;
    }
}

extern "C" void kernel_launch(void* const* d_in, const int* in_sizes, int n_in,
                              void* d_out, int out_size, void* d_ws, size_t ws_size,
                              hipStream_t stream) {
    const float* feats  = (const float*)d_in[0];   // (B,128) f32
    const int*   labels = (const int*)d_in[1];     // (B,)    i32
    const float* prior  = (const float*)d_in[2];   // (1000,) f32
    const float* z_bar  = (const float*)d_in[3];   // (1000,128) f32
    float* out = (float*)d_out;
    const int B = in_sizes[1];

    // ws (floats): kmF 65536 | cls_c 1024 | cls_sq 1024 | T 4104 | Pm 2B | Ps 2B | Pn 2B
    float* ws      = (float*)d_ws;
    float* kmFf    = ws;
    float* cls_c   = kmFf + 65536;
    float* cls_sq  = cls_c + K_PAD;
    float* T       = cls_sq + K_PAD;
    float* Pm      = T + 4104;
    float* Ps      = Pm + 2 * B;
    float* Pn      = Ps + 2 * B;

    prep_kernel<<<81, 256, 0, stream>>>(z_bar, prior, (short8v*)kmFf, cls_c, cls_sq, T);
    main_kernel<<<(B / 16) * 2, 256, 0, stream>>>(feats, labels, (const short8v*)kmFf,
                                                  cls_c, cls_sq, T, Pm, Ps, Pn);
    reduce_kernel<<<1, 1024, 0, stream>>>(Pm, Ps, Pn, out, B);
}